// Round 1
// baseline (646.647 us; speedup 1.0000x reference)
//
#include <hip/hip_runtime.h>

// Problem constants (fixed by setup_inputs)
#define HW   256
#define Bb   4
#define Nn   256       // B*K flattened keypoints
#define Pp   33
#define PPAD 36        // padded patch row (16B-aligned float4 tiles)
#define C1   32
#define C2   64
#define OUTF 128
#define S1   31        // conv1 out spatial
#define S2   15        // conv2 out spatial
#define SIG  16

// ws layout (float offsets)
#define WS_W1T  0        // [27][32]   = 864
#define WS_W2T  864      // [288][64]  = 18432
#define WS_WLT  19296    // [64][128]  = 8192
#define WS_FEAT 27488    // 2*256*4*128 = 262144
#define WS_PART 289632   // 64 doubles (byte offset 1158528, 8B aligned)
#define FEAT_PER_SIDE (Nn * Bb * OUTF)   // 131072

__global__ __launch_bounds__(256) void prep_kernel(
    const float* __restrict__ w1, const float* __restrict__ w2,
    const float* __restrict__ wl, float* __restrict__ ws) {
  int t = blockIdx.x * 256 + threadIdx.x;
  int stride = gridDim.x * 256;
  // w1t[k][ch]: k=(ci*3+ky)*3+kx, w1 is [ch][ci][ky][kx] = ch*27+k
  for (int i = t; i < 864; i += stride) {
    int ch = i & 31, k = i >> 5;
    ws[WS_W1T + i] = w1[ch * 27 + k];
  }
  // w2t[k][ch]: k=(kc*3+ky)*3+kx (kc<32), w2 is [ch][kc][ky][kx] = ch*288+k
  for (int i = t; i < 18432; i += stride) {
    int ch = i & 63, k = i >> 6;
    ws[WS_W2T + i] = w2[ch * 288 + k];
  }
  // wlt[i64][o128]: wl is [o][i] = o*64+i
  for (int i = t; i < 8192; i += stride) {
    int o = i & 127, ii = i >> 7;
    ws[WS_WLT + i] = wl[o * 64 + ii];
  }
}

__global__ __launch_bounds__(256) void patch_cnn_kernel(
    const float* __restrict__ imgG, const float* __restrict__ imgS,
    const float* __restrict__ kpG,  const float* __restrict__ kpS,
    const float* __restrict__ b1g,  const float* __restrict__ b2g,
    const float* __restrict__ blg,  float* __restrict__ ws) {
  __shared__ __align__(16) float patch[3 * Pp * PPAD];   // 3564 f
  __shared__ __align__(16) float strip[9 * 8 * 32];      // 2304 f: [rr][kcl][col32]
  __shared__ __align__(16) float w2c[8 * 9 * 64];        // 4608 f: [kc2][kyky*3+kx][ch]
  __shared__ __align__(16) float w1l[27 * 32];           // 864 f
  __shared__ float b1l[32];
  __shared__ float gapP[4 * 64];
  __shared__ float gapv[64];

  const int bid  = blockIdx.x;
  const int side = bid >> 10;
  const int rem  = bid & 1023;
  const int n    = rem >> 2;
  const int b    = rem & 3;
  const float* img = side ? imgS : imgG;
  const float* kp  = side ? kpS : kpG;
  const int tid  = threadIdx.x;
  const int wave = tid >> 6;
  const int lane = tid & 63;

  // keypoint -> crop start (matches floor(kp*256)-16 clipped to [0,223])
  int sx = (int)floorf(kp[n * 2 + 0] * 256.0f) - SIG;
  int sy = (int)floorf(kp[n * 2 + 1] * 256.0f) - SIG;
  sx = min(max(sx, 0), HW - Pp);
  sy = min(max(sy, 0), HW - Pp);

  // stage patch (zero the pad cols so tile-overreads are benign)
  for (int i = tid; i < 3 * Pp * PPAD; i += 256) {
    int ci = i / (Pp * PPAD);
    int r2 = i - ci * (Pp * PPAD);
    int r  = r2 / PPAD;
    int cc = r2 - r * PPAD;
    float v = 0.0f;
    if (cc < Pp) v = img[((b * 3 + ci) * HW + (sy + r)) * HW + (sx + cc)];
    patch[i] = v;
  }
  for (int i = tid; i < 864; i += 256) w1l[i] = ws[WS_W1T + i];
  if (tid < 32) b1l[tid] = b1g[tid];

  const float b2v = b2g[lane];   // lane == conv2 channel
  float gapAcc = 0.0f;
  __syncthreads();

  for (int g = 0; g < 16; g += 4) {        // y2 group: wave w handles y2=g+w
    float acc[15];
#pragma unroll
    for (int x = 0; x < 15; ++x) acc[x] = 0.0f;
    const int y2 = g + wave;
    const bool act = (y2 < 15);

    for (int c = 0; c < 4; ++c) {          // kc chunk of 8
      // stage w2 chunk (contiguous in w2t)
      for (int i = tid; i < 4608; i += 256) w2c[i] = ws[WS_W2T + c * 4608 + i];
      // conv1 strip: rows rr=0..8 (abs R=2g+rr), ch = c*8 + (lane&7)
      {
        const int kcl  = lane & 7;
        const int tpos = lane >> 3;        // col tile: 4*tpos .. 4*tpos+3
        for (int rr = wave; rr < 9; rr += 4) {
          const int R = 2 * g + rr;
          if (R <= 30) {
            const float bb = b1l[c * 8 + kcl];
            float a0 = bb, a1 = bb, a2 = bb, a3 = bb;
#pragma unroll
            for (int ci = 0; ci < 3; ++ci) {
#pragma unroll
              for (int kyy = 0; kyy < 3; ++kyy) {
                const float* prow = &patch[(ci * Pp + R + kyy) * PPAD + tpos * 4];
                float4 v0 = *(const float4*)prow;
                float4 v1 = *(const float4*)(prow + 4);
                float vv[8] = {v0.x, v0.y, v0.z, v0.w, v1.x, v1.y, v1.z, v1.w};
#pragma unroll
                for (int kxx = 0; kxx < 3; ++kxx) {
                  const float w = w1l[((ci * 3 + kyy) * 3 + kxx) * 32 + c * 8 + kcl];
                  a0 = fmaf(vv[0 + kxx], w, a0);
                  a1 = fmaf(vv[1 + kxx], w, a1);
                  a2 = fmaf(vv[2 + kxx], w, a2);
                  a3 = fmaf(vv[3 + kxx], w, a3);
                }
              }
            }
            float4 o;
            o.x = fmaxf(a0, 0.0f); o.y = fmaxf(a1, 0.0f);
            o.z = fmaxf(a2, 0.0f); o.w = fmaxf(a3, 0.0f);
            *(float4*)&strip[(rr * 8 + kcl) * 32 + tpos * 4] = o;   // col31 pad: never used
          }
        }
      }
      __syncthreads();
      // conv2 partial: lane=ch, 15 col accumulators, wave-uniform strip reads
      if (act) {
#pragma unroll
        for (int kc2 = 0; kc2 < 8; ++kc2) {
#pragma unroll
          for (int kyy = 0; kyy < 3; ++kyy) {
            const int rr = 2 * wave + kyy;
            const float4* srow = (const float4*)&strip[(rr * 8 + kc2) * 32];
            float v[32];
#pragma unroll
            for (int j = 0; j < 8; ++j) ((float4*)v)[j] = srow[j];
            const int wb = (kc2 * 9 + kyy * 3) * 64 + lane;
            const float w0 = w2c[wb], w1v = w2c[wb + 64], w2v = w2c[wb + 128];
#pragma unroll
            for (int x = 0; x < 15; ++x)
              acc[x] = fmaf(v[2 * x], w0,
                       fmaf(v[2 * x + 1], w1v,
                       fmaf(v[2 * x + 2], w2v, acc[x])));
          }
        }
      }
      __syncthreads();
    }
    if (act) {
      float rs = 0.0f;
#pragma unroll
      for (int x = 0; x < 15; ++x) rs += fmaxf(acc[x] + b2v, 0.0f);
      gapAcc += rs;
    }
  }

  gapP[wave * 64 + lane] = gapAcc;
  __syncthreads();
  if (tid < 64)
    gapv[tid] = (gapP[tid] + gapP[64 + tid] + gapP[128 + tid] + gapP[192 + tid]) *
                (1.0f / 225.0f);
  __syncthreads();
  if (tid < OUTF) {
    float f = blg[tid];
#pragma unroll 4
    for (int i = 0; i < 64; ++i) f = fmaf(gapv[i], ws[WS_WLT + i * OUTF + tid], f);
    ws[WS_FEAT + ((side * Nn + n) * Bb + b) * OUTF + tid] = f;
  }
}

__global__ __launch_bounds__(256) void loss_part(const float* __restrict__ wsf,
                                                 double* __restrict__ parts) {
  const float* fg = wsf + WS_FEAT;
  const float* fs = fg + FEAT_PER_SIDE;
  double s = 0.0;
  for (int i = blockIdx.x * 256 + threadIdx.x; i < FEAT_PER_SIDE; i += 64 * 256) {
    double d = (double)fg[i] - (double)fs[i];
    s += d * d;
  }
  __shared__ double red[256];
  red[threadIdx.x] = s;
  __syncthreads();
  for (int off = 128; off > 0; off >>= 1) {
    if (threadIdx.x < off) red[threadIdx.x] += red[threadIdx.x + off];
    __syncthreads();
  }
  if (threadIdx.x == 0) parts[blockIdx.x] = red[0];
}

__global__ void loss_final(float* __restrict__ out, const double* __restrict__ parts) {
  double s = parts[threadIdx.x];           // 64 threads, one wave
#pragma unroll
  for (int off = 32; off > 0; off >>= 1) s += __shfl_down(s, off, 64);
  if (threadIdx.x == 0) out[0] = (float)(s / (double)FEAT_PER_SIDE);
}

extern "C" void kernel_launch(void* const* d_in, const int* in_sizes, int n_in,
                              void* d_out, int out_size, void* d_ws, size_t ws_size,
                              hipStream_t stream) {
  const float* imgG = (const float*)d_in[0];
  const float* imgS = (const float*)d_in[1];
  const float* kpG  = (const float*)d_in[2];
  const float* kpS  = (const float*)d_in[3];
  const float* w1   = (const float*)d_in[4];
  const float* b1   = (const float*)d_in[5];
  const float* w2   = (const float*)d_in[6];
  const float* b2   = (const float*)d_in[7];
  const float* wl   = (const float*)d_in[8];
  const float* bl   = (const float*)d_in[9];
  float* ws  = (float*)d_ws;
  float* out = (float*)d_out;
  double* parts = (double*)((char*)d_ws + (size_t)WS_PART * 4);

  hipLaunchKernelGGL(prep_kernel, dim3(32), dim3(256), 0, stream, w1, w2, wl, ws);
  hipLaunchKernelGGL(patch_cnn_kernel, dim3(2048), dim3(256), 0, stream,
                     imgG, imgS, kpG, kpS, b1, b2, bl, ws);
  hipLaunchKernelGGL(loss_part, dim3(64), dim3(256), 0, stream, ws, parts);
  hipLaunchKernelGGL(loss_final, dim3(1), dim3(64), 0, stream, out, parts);
}

// Round 2
// 362.643 us; speedup vs baseline: 1.7831x; 1.7831x over previous
//
#include <hip/hip_runtime.h>

// Problem constants (fixed by setup_inputs)
#define HW   256
#define Bb   4
#define Nn   256       // B*K flattened keypoints
#define Pp   33
#define PPAD 36        // padded patch row
#define OUTF 128
#define SIG  16

// ws layout (float offsets)
#define WS_W1T  0        // [27][32]   = 864
#define WS_W2T  864      // [288][64]  = 18432
#define WS_WLT  19296    // [64][128]  = 8192
#define WS_FEAT 27488    // 2*256*4*128 = 262144
#define WS_PART 289632   // 64 doubles (byte offset 1158528, 8B aligned)
#define FEAT_PER_SIDE (Nn * Bb * OUTF)   // 131072

__global__ __launch_bounds__(256) void prep_kernel(
    const float* __restrict__ w1, const float* __restrict__ w2,
    const float* __restrict__ wl, float* __restrict__ ws) {
  int t = blockIdx.x * 256 + threadIdx.x;
  int stride = gridDim.x * 256;
  for (int i = t; i < 864; i += stride) {        // w1t[k27][ch32]
    int ch = i & 31, k = i >> 5;
    ws[WS_W1T + i] = w1[ch * 27 + k];
  }
  for (int i = t; i < 18432; i += stride) {      // w2t[k288][ch64]
    int ch = i & 63, k = i >> 6;
    ws[WS_W2T + i] = w2[ch * 288 + k];
  }
  for (int i = t; i < 8192; i += stride) {       // wlt[i64][o128]
    int o = i & 127, ii = i >> 7;
    ws[WS_WLT + i] = wl[o * 64 + ii];
  }
}

// One block per patch. 256 threads = 4 waves.
// conv2 mapping: thread = y2*16 + chg; owns 15 x-positions x 4 channels (acc[15] float4).
// conv1 mapping: lane = (rpar<<5)|(kcl<<3)|tpos; kc-chunks of 4 across 8 chunk iters.
__global__ __launch_bounds__(256, 3) void patch_cnn_kernel(
    const float* __restrict__ imgG, const float* __restrict__ imgS,
    const float* __restrict__ kpG,  const float* __restrict__ kpS,
    const float* __restrict__ b1g,  const float* __restrict__ b2g,
    const float* __restrict__ blg,  float* __restrict__ ws) {
  __shared__ __align__(16) float patch[3 * Pp * PPAD];   // 3564 f
  __shared__ __align__(16) float strip[4 * 31 * 32];     // 3968 f: [kc4][R31][col32]
  __shared__ __align__(16) float w2c[4 * 9 * 64];        // 2304 f: [kc4][tap9][ch64]
  __shared__ __align__(16) float w1l[27 * 32];           // 864 f
  __shared__ float b1l[32];
  __shared__ __align__(16) float gapP[16 * 64];          // 1024 f
  __shared__ float gapv[64];
  // total = 47,280 B -> 3 blocks/CU

  const int bid  = blockIdx.x;
  const int side = bid >> 10;
  const int rem  = bid & 1023;
  const int n    = rem >> 2;
  const int b    = rem & 3;
  const float* img = side ? imgS : imgG;
  const float* kp  = side ? kpS : kpG;
  const int tid  = threadIdx.x;
  const int wave = tid >> 6;
  const int lane = tid & 63;

  // conv1 lane mapping (tpos innermost -> conflict-free strip writes)
  const int tpos = lane & 7;
  const int kcl  = (lane >> 3) & 3;
  const int rpar = lane >> 5;
  // conv2 thread mapping
  const int y2  = tid >> 4;       // 0..15 (15 = inactive)
  const int chg = tid & 15;
  const bool c2act = (y2 < 15);

  int sx = (int)floorf(kp[n * 2 + 0] * 256.0f) - SIG;
  int sy = (int)floorf(kp[n * 2 + 1] * 256.0f) - SIG;
  sx = min(max(sx, 0), HW - Pp);
  sy = min(max(sy, 0), HW - Pp);

  // stage patch (zero pad cols)
  for (int i = tid; i < 3 * Pp * PPAD; i += 256) {
    int ci = i / (Pp * PPAD);
    int r2 = i - ci * (Pp * PPAD);
    int r  = r2 / PPAD;
    int cc = r2 - r * PPAD;
    float v = 0.0f;
    if (cc < Pp) v = img[((b * 3 + ci) * HW + (sy + r)) * HW + (sx + cc)];
    patch[i] = v;
  }
  for (int i = tid; i < 864; i += 256) w1l[i] = ws[WS_W1T + i];
  if (tid < 32) b1l[tid] = b1g[tid];

  float4 acc[15];
#pragma unroll
  for (int x = 0; x < 15; ++x) acc[x] = make_float4(0.f, 0.f, 0.f, 0.f);

  __syncthreads();

  for (int c = 0; c < 8; ++c) {    // kc chunk of 4 input channels
    // stage w2 chunk: [4][9][64] contiguous in w2t
    {
      const float4* src = (const float4*)(ws + WS_W2T + c * 2304);
      float4* dst = (float4*)w2c;
      for (int i = tid; i < 576; i += 256) dst[i] = src[i];
    }
    // conv1: channels c*4 .. c*4+3, all 31 rows into strip
    {
      const int ch1 = c * 4 + kcl;
      const float bb = b1l[ch1];
      float wr[27];
#pragma unroll
      for (int k = 0; k < 27; ++k) wr[k] = w1l[k * 32 + ch1];
      float* sptr = &strip[kcl * 992 + tpos * 4];
      for (int r = wave; r < 16; r += 4) {
        const int R = 2 * r + rpar;
        if (R < 31) {
          float a0 = bb, a1 = bb, a2 = bb, a3 = bb;
#pragma unroll
          for (int ci = 0; ci < 3; ++ci) {
#pragma unroll
            for (int ky = 0; ky < 3; ++ky) {
              const float* pr = &patch[(ci * Pp + R + ky) * PPAD + tpos * 4];
              float4 v0 = *(const float4*)pr;
              float2 v1 = *(const float2*)(pr + 4);
              const int k = (ci * 3 + ky) * 3;
              a0 = fmaf(v0.z, wr[k + 2], fmaf(v0.y, wr[k + 1], fmaf(v0.x, wr[k], a0)));
              a1 = fmaf(v0.w, wr[k + 2], fmaf(v0.z, wr[k + 1], fmaf(v0.y, wr[k], a1)));
              a2 = fmaf(v1.x, wr[k + 2], fmaf(v0.w, wr[k + 1], fmaf(v0.z, wr[k], a2)));
              a3 = fmaf(v1.y, wr[k + 2], fmaf(v1.x, wr[k + 1], fmaf(v0.w, wr[k], a3)));
            }
          }
          float4 o;
          o.x = fmaxf(a0, 0.f); o.y = fmaxf(a1, 0.f);
          o.z = fmaxf(a2, 0.f); o.w = fmaxf(a3, 0.f);
          *(float4*)(sptr + R * 32) = o;
        }
      }
    }
    __syncthreads();
    // conv2: each active thread does 4kc x 3ky x (15x * 4ch * 3kx) FMAs
    if (c2act) {
      const float* sbase = &strip[2 * y2 * 32];
#pragma unroll 1
      for (int kc = 0; kc < 4; ++kc) {
        const float* srow = sbase + kc * 992;
        const float4* wk = (const float4*)&w2c[kc * 576 + 4 * chg];
        float4 wq[9];
#pragma unroll
        for (int q = 0; q < 9; ++q) wq[q] = wk[q * 16];
#pragma unroll
        for (int ky = 0; ky < 3; ++ky) {
          float v[32];
          const float4* sv = (const float4*)(srow + ky * 32);
#pragma unroll
          for (int j = 0; j < 8; ++j) ((float4*)v)[j] = sv[j];
          const float4 w0 = wq[ky * 3], w1v = wq[ky * 3 + 1], w2v = wq[ky * 3 + 2];
#pragma unroll
          for (int x = 0; x < 15; ++x) {
            float4 a = acc[x];
            a.x = fmaf(v[2*x+2], w2v.x, fmaf(v[2*x+1], w1v.x, fmaf(v[2*x], w0.x, a.x)));
            a.y = fmaf(v[2*x+2], w2v.y, fmaf(v[2*x+1], w1v.y, fmaf(v[2*x], w0.y, a.y)));
            a.z = fmaf(v[2*x+2], w2v.z, fmaf(v[2*x+1], w1v.z, fmaf(v[2*x], w0.z, a.z)));
            a.w = fmaf(v[2*x+2], w2v.w, fmaf(v[2*x+1], w1v.w, fmaf(v[2*x], w0.w, a.w)));
            acc[x] = a;
          }
        }
      }
    }
    __syncthreads();
  }

  // epilogue: bias + relu + GAP partial per (y2, 4ch)
  if (c2act) {
    const float4 b2v = *(const float4*)(b2g + 4 * chg);
    float4 s = make_float4(0.f, 0.f, 0.f, 0.f);
#pragma unroll
    for (int x = 0; x < 15; ++x) {
      s.x += fmaxf(acc[x].x + b2v.x, 0.f);
      s.y += fmaxf(acc[x].y + b2v.y, 0.f);
      s.z += fmaxf(acc[x].z + b2v.z, 0.f);
      s.w += fmaxf(acc[x].w + b2v.w, 0.f);
    }
    *(float4*)&gapP[y2 * 64 + 4 * chg] = s;
  } else {
    *(float4*)&gapP[15 * 64 + 4 * (tid - 240)] = make_float4(0.f, 0.f, 0.f, 0.f);
  }
  __syncthreads();
  if (tid < 64) {
    float s = 0.f;
#pragma unroll
    for (int y = 0; y < 16; ++y) s += gapP[y * 64 + tid];
    gapv[tid] = s * (1.0f / 225.0f);
  }
  __syncthreads();
  if (tid < OUTF) {
    float f = blg[tid];
#pragma unroll 8
    for (int i = 0; i < 64; ++i) f = fmaf(gapv[i], ws[WS_WLT + i * OUTF + tid], f);
    ws[WS_FEAT + ((side * Nn + n) * Bb + b) * OUTF + tid] = f;
  }
}

__global__ __launch_bounds__(256) void loss_part(const float* __restrict__ wsf,
                                                 double* __restrict__ parts) {
  const float* fg = wsf + WS_FEAT;
  const float* fs = fg + FEAT_PER_SIDE;
  double s = 0.0;
  for (int i = blockIdx.x * 256 + threadIdx.x; i < FEAT_PER_SIDE; i += 64 * 256) {
    double d = (double)fg[i] - (double)fs[i];
    s += d * d;
  }
  __shared__ double red[256];
  red[threadIdx.x] = s;
  __syncthreads();
  for (int off = 128; off > 0; off >>= 1) {
    if (threadIdx.x < off) red[threadIdx.x] += red[threadIdx.x + off];
    __syncthreads();
  }
  if (threadIdx.x == 0) parts[blockIdx.x] = red[0];
}

__global__ void loss_final(float* __restrict__ out, const double* __restrict__ parts) {
  double s = parts[threadIdx.x];
#pragma unroll
  for (int off = 32; off > 0; off >>= 1) s += __shfl_down(s, off, 64);
  if (threadIdx.x == 0) out[0] = (float)(s / (double)FEAT_PER_SIDE);
}

extern "C" void kernel_launch(void* const* d_in, const int* in_sizes, int n_in,
                              void* d_out, int out_size, void* d_ws, size_t ws_size,
                              hipStream_t stream) {
  const float* imgG = (const float*)d_in[0];
  const float* imgS = (const float*)d_in[1];
  const float* kpG  = (const float*)d_in[2];
  const float* kpS  = (const float*)d_in[3];
  const float* w1   = (const float*)d_in[4];
  const float* b1   = (const float*)d_in[5];
  const float* w2   = (const float*)d_in[6];
  const float* b2   = (const float*)d_in[7];
  const float* wl   = (const float*)d_in[8];
  const float* bl   = (const float*)d_in[9];
  float* ws  = (float*)d_ws;
  float* out = (float*)d_out;
  double* parts = (double*)((char*)d_ws + (size_t)WS_PART * 4);

  hipLaunchKernelGGL(prep_kernel, dim3(32), dim3(256), 0, stream, w1, w2, wl, ws);
  hipLaunchKernelGGL(patch_cnn_kernel, dim3(2048), dim3(256), 0, stream,
                     imgG, imgS, kpG, kpS, b1, b2, bl, ws);
  hipLaunchKernelGGL(loss_part, dim3(64), dim3(256), 0, stream, ws, parts);
  hipLaunchKernelGGL(loss_final, dim3(1), dim3(64), 0, stream, out, parts);
}

// Round 3
// 350.914 us; speedup vs baseline: 1.8427x; 1.0334x over previous
//
#include <hip/hip_runtime.h>

// Problem constants (fixed by setup_inputs)
#define HW   256
#define Bb   4
#define Nn   256       // B*K flattened keypoints
#define Pp   33
#define PPAD 36        // padded patch row
#define OUTF 128
#define SIG  16

// strip layout: [kc4][R31][col 36 (32 used + 4 pad)]
// stride 36 (not 32): 36 mod 32 = 4, 31*36=1116 mod 32 = 28 -> banks spread.
// With stride 32 both were =0 mod 32 -> 4-way read / 8-way write conflicts
// (measured SQ_LDS_BANK_CONFLICT 2.5e7 = ~41 us of stall).
#define SSTR 36
#define SKC  (31 * SSTR)   // 1116

// ws layout (float offsets)
#define WS_W1T  0        // [27][32]   = 864
#define WS_W2T  864      // [288][64]  = 18432
#define WS_WLT  19296    // [64][128]  = 8192
#define WS_FEAT 27488    // 2*256*4*128 = 262144
#define WS_PART 289632   // 64 doubles (byte offset 1158528, 8B aligned)
#define FEAT_PER_SIDE (Nn * Bb * OUTF)   // 131072

__global__ __launch_bounds__(256) void prep_kernel(
    const float* __restrict__ w1, const float* __restrict__ w2,
    const float* __restrict__ wl, float* __restrict__ ws) {
  int t = blockIdx.x * 256 + threadIdx.x;
  int stride = gridDim.x * 256;
  for (int i = t; i < 864; i += stride) {        // w1t[k27][ch32]
    int ch = i & 31, k = i >> 5;
    ws[WS_W1T + i] = w1[ch * 27 + k];
  }
  for (int i = t; i < 18432; i += stride) {      // w2t[k288][ch64]
    int ch = i & 63, k = i >> 6;
    ws[WS_W2T + i] = w2[ch * 288 + k];
  }
  for (int i = t; i < 8192; i += stride) {       // wlt[i64][o128]
    int o = i & 127, ii = i >> 7;
    ws[WS_WLT + i] = wl[o * 64 + ii];
  }
}

// One block per patch. 256 threads = 4 waves.
// conv2 mapping: thread = y2*16 + chg; owns 15 x-positions x 4 channels.
// conv1 mapping: lane = (rpar<<5)|(kcl<<3)|tpos; kc-chunks of 4 across 8 iters.
__global__ __launch_bounds__(256, 3) void patch_cnn_kernel(
    const float* __restrict__ imgG, const float* __restrict__ imgS,
    const float* __restrict__ kpG,  const float* __restrict__ kpS,
    const float* __restrict__ b1g,  const float* __restrict__ b2g,
    const float* __restrict__ blg,  float* __restrict__ ws) {
  __shared__ __align__(16) float patch[3 * Pp * PPAD];   // 3564 f
  __shared__ __align__(16) float strip[4 * SKC];         // 4464 f (padded stride)
  __shared__ __align__(16) float w2c[4 * 9 * 64];        // 2304 f
  __shared__ __align__(16) float w1l[27 * 32];           // 864 f
  __shared__ float b1l[32];
  __shared__ __align__(16) float gapP[16 * 64];          // 1024 f
  __shared__ float gapv[64];
  // total = 49,264 B -> 3 blocks/CU

  const int bid  = blockIdx.x;
  const int side = bid >> 10;
  const int rem  = bid & 1023;
  const int n    = rem >> 2;
  const int b    = rem & 3;
  const float* img = side ? imgS : imgG;
  const float* kp  = side ? kpS : kpG;
  const int tid  = threadIdx.x;
  const int wave = tid >> 6;
  const int lane = tid & 63;

  // conv1 lane mapping
  const int tpos = lane & 7;
  const int kcl  = (lane >> 3) & 3;
  const int rpar = lane >> 5;
  // conv2 thread mapping
  const int y2  = tid >> 4;       // 0..15 (15 = inactive)
  const int chg = tid & 15;
  const bool c2act = (y2 < 15);

  int sx = (int)floorf(kp[n * 2 + 0] * 256.0f) - SIG;
  int sy = (int)floorf(kp[n * 2 + 1] * 256.0f) - SIG;
  sx = min(max(sx, 0), HW - Pp);
  sy = min(max(sy, 0), HW - Pp);

  // stage patch (zero pad cols)
  for (int i = tid; i < 3 * Pp * PPAD; i += 256) {
    int ci = i / (Pp * PPAD);
    int r2 = i - ci * (Pp * PPAD);
    int r  = r2 / PPAD;
    int cc = r2 - r * PPAD;
    float v = 0.0f;
    if (cc < Pp) v = img[((b * 3 + ci) * HW + (sy + r)) * HW + (sx + cc)];
    patch[i] = v;
  }
  for (int i = tid; i < 864; i += 256) w1l[i] = ws[WS_W1T + i];
  if (tid < 32) b1l[tid] = b1g[tid];

  float4 acc[15];
#pragma unroll
  for (int x = 0; x < 15; ++x) acc[x] = make_float4(0.f, 0.f, 0.f, 0.f);

  __syncthreads();

  for (int c = 0; c < 8; ++c) {    // kc chunk of 4 input channels
    // stage w2 chunk: [4][9][64] contiguous in w2t
    {
      const float4* src = (const float4*)(ws + WS_W2T + c * 2304);
      float4* dst = (float4*)w2c;
      for (int i = tid; i < 576; i += 256) dst[i] = src[i];
    }
    // conv1: channels c*4 .. c*4+3, all 31 rows into strip
    {
      const int ch1 = c * 4 + kcl;
      const float bb = b1l[ch1];
      float wr[27];
#pragma unroll
      for (int k = 0; k < 27; ++k) wr[k] = w1l[k * 32 + ch1];
      float* sptr = &strip[kcl * SKC + tpos * 4];
      for (int r = wave; r < 16; r += 4) {
        const int R = 2 * r + rpar;
        if (R < 31) {
          float a0 = bb, a1 = bb, a2 = bb, a3 = bb;
#pragma unroll
          for (int ci = 0; ci < 3; ++ci) {
#pragma unroll
            for (int ky = 0; ky < 3; ++ky) {
              const float* pr = &patch[(ci * Pp + R + ky) * PPAD + tpos * 4];
              float4 v0 = *(const float4*)pr;
              float2 v1 = *(const float2*)(pr + 4);
              const int k = (ci * 3 + ky) * 3;
              a0 = fmaf(v0.z, wr[k + 2], fmaf(v0.y, wr[k + 1], fmaf(v0.x, wr[k], a0)));
              a1 = fmaf(v0.w, wr[k + 2], fmaf(v0.z, wr[k + 1], fmaf(v0.y, wr[k], a1)));
              a2 = fmaf(v1.x, wr[k + 2], fmaf(v0.w, wr[k + 1], fmaf(v0.z, wr[k], a2)));
              a3 = fmaf(v1.y, wr[k + 2], fmaf(v1.x, wr[k + 1], fmaf(v0.w, wr[k], a3)));
            }
          }
          float4 o;
          o.x = fmaxf(a0, 0.f); o.y = fmaxf(a1, 0.f);
          o.z = fmaxf(a2, 0.f); o.w = fmaxf(a3, 0.f);
          *(float4*)(sptr + R * SSTR) = o;
        }
      }
    }
    __syncthreads();
    // conv2: each active thread does 4kc x 3ky x (15x * 4ch * 3kx) FMAs
    if (c2act) {
      const float* sbase = &strip[2 * y2 * SSTR];
#pragma unroll 1
      for (int kc = 0; kc < 4; ++kc) {
        const float* srow = sbase + kc * SKC;
        const float4* wk = (const float4*)&w2c[kc * 576 + 4 * chg];
        float4 wq[9];
#pragma unroll
        for (int q = 0; q < 9; ++q) wq[q] = wk[q * 16];
#pragma unroll
        for (int ky = 0; ky < 3; ++ky) {
          float v[32];
          const float4* sv = (const float4*)(srow + ky * SSTR);
#pragma unroll
          for (int j = 0; j < 8; ++j) ((float4*)v)[j] = sv[j];
          const float4 w0 = wq[ky * 3], w1v = wq[ky * 3 + 1], w2v = wq[ky * 3 + 2];
#pragma unroll
          for (int x = 0; x < 15; ++x) {
            float4 a = acc[x];
            a.x = fmaf(v[2*x+2], w2v.x, fmaf(v[2*x+1], w1v.x, fmaf(v[2*x], w0.x, a.x)));
            a.y = fmaf(v[2*x+2], w2v.y, fmaf(v[2*x+1], w1v.y, fmaf(v[2*x], w0.y, a.y)));
            a.z = fmaf(v[2*x+2], w2v.z, fmaf(v[2*x+1], w1v.z, fmaf(v[2*x], w0.z, a.z)));
            a.w = fmaf(v[2*x+2], w2v.w, fmaf(v[2*x+1], w1v.w, fmaf(v[2*x], w0.w, a.w)));
            acc[x] = a;
          }
        }
      }
    }
    __syncthreads();
  }

  // epilogue: bias + relu + GAP partial per (y2, 4ch)
  if (c2act) {
    const float4 b2v = *(const float4*)(b2g + 4 * chg);
    float4 s = make_float4(0.f, 0.f, 0.f, 0.f);
#pragma unroll
    for (int x = 0; x < 15; ++x) {
      s.x += fmaxf(acc[x].x + b2v.x, 0.f);
      s.y += fmaxf(acc[x].y + b2v.y, 0.f);
      s.z += fmaxf(acc[x].z + b2v.z, 0.f);
      s.w += fmaxf(acc[x].w + b2v.w, 0.f);
    }
    *(float4*)&gapP[y2 * 64 + 4 * chg] = s;
  } else {
    *(float4*)&gapP[15 * 64 + 4 * (tid - 240)] = make_float4(0.f, 0.f, 0.f, 0.f);
  }
  __syncthreads();
  if (tid < 64) {
    float s = 0.f;
#pragma unroll
    for (int y = 0; y < 16; ++y) s += gapP[y * 64 + tid];
    gapv[tid] = s * (1.0f / 225.0f);
  }
  __syncthreads();
  if (tid < OUTF) {
    float f = blg[tid];
#pragma unroll 8
    for (int i = 0; i < 64; ++i) f = fmaf(gapv[i], ws[WS_WLT + i * OUTF + tid], f);
    ws[WS_FEAT + ((side * Nn + n) * Bb + b) * OUTF + tid] = f;
  }
}

__global__ __launch_bounds__(256) void loss_part(const float* __restrict__ wsf,
                                                 double* __restrict__ parts) {
  const float* fg = wsf + WS_FEAT;
  const float* fs = fg + FEAT_PER_SIDE;
  double s = 0.0;
  for (int i = blockIdx.x * 256 + threadIdx.x; i < FEAT_PER_SIDE; i += 64 * 256) {
    double d = (double)fg[i] - (double)fs[i];
    s += d * d;
  }
  __shared__ double red[256];
  red[threadIdx.x] = s;
  __syncthreads();
  for (int off = 128; off > 0; off >>= 1) {
    if (threadIdx.x < off) red[threadIdx.x] += red[threadIdx.x + off];
    __syncthreads();
  }
  if (threadIdx.x == 0) parts[blockIdx.x] = red[0];
}

__global__ void loss_final(float* __restrict__ out, const double* __restrict__ parts) {
  double s = parts[threadIdx.x];
#pragma unroll
  for (int off = 32; off > 0; off >>= 1) s += __shfl_down(s, off, 64);
  if (threadIdx.x == 0) out[0] = (float)(s / (double)FEAT_PER_SIDE);
}

extern "C" void kernel_launch(void* const* d_in, const int* in_sizes, int n_in,
                              void* d_out, int out_size, void* d_ws, size_t ws_size,
                              hipStream_t stream) {
  const float* imgG = (const float*)d_in[0];
  const float* imgS = (const float*)d_in[1];
  const float* kpG  = (const float*)d_in[2];
  const float* kpS  = (const float*)d_in[3];
  const float* w1   = (const float*)d_in[4];
  const float* b1   = (const float*)d_in[5];
  const float* w2   = (const float*)d_in[6];
  const float* b2   = (const float*)d_in[7];
  const float* wl   = (const float*)d_in[8];
  const float* bl   = (const float*)d_in[9];
  float* ws  = (float*)d_ws;
  float* out = (float*)d_out;
  double* parts = (double*)((char*)d_ws + (size_t)WS_PART * 4);

  hipLaunchKernelGGL(prep_kernel, dim3(32), dim3(256), 0, stream, w1, w2, wl, ws);
  hipLaunchKernelGGL(patch_cnn_kernel, dim3(2048), dim3(256), 0, stream,
                     imgG, imgS, kpG, kpS, b1, b2, bl, ws);
  hipLaunchKernelGGL(loss_part, dim3(64), dim3(256), 0, stream, ws, parts);
  hipLaunchKernelGGL(loss_final, dim3(1), dim3(64), 0, stream, out, parts);
}